// Round 7
// baseline (1139.701 us; speedup 1.0000x reference)
//
#include <hip/hip_runtime.h>
#include <hip/hip_bf16.h>
#include <math.h>

typedef __attribute__((ext_vector_type(8))) short short8;
typedef __attribute__((ext_vector_type(4))) float f32x4;
typedef __attribute__((ext_vector_type(16))) float f32x16;
typedef __attribute__((ext_vector_type(4))) unsigned int u32x4;
typedef __attribute__((ext_vector_type(2))) int i32x2;

#define BATCH   2
#define SLEN    2048
#define DMODEL  4096
#define NHEADS  32
#define KVHEADS 8
#define HD      128
#define KVDIM   (KVHEADS*HD)   // 1024
#define MROWS   (BATCH*SLEN)   // 4096

// async global->LDS, 16B per lane, dest = wave-uniform base + lane*16
#define GLDS16(gp, lp) __builtin_amdgcn_global_load_lds( \
    (const __attribute__((address_space(1))) void*)(gp), \
    (__attribute__((address_space(3))) void*)(lp), 16, 0, 0)

static __device__ __forceinline__ unsigned short bf16bits(float x) {
    __hip_bfloat16 h = __float2bfloat16(x);
    return *(unsigned short*)&h;
}
static __device__ __forceinline__ float bf2f(unsigned short u) {
    __hip_bfloat16 h = *(__hip_bfloat16*)&u;
    return __bfloat162float(h);
}
// v_cvt_pk_bf16_f32: lo=src0, hi=src1 (no builtin on gfx950)
static __device__ __forceinline__ unsigned cvtpk(float a, float b) {
    unsigned r;
    asm("v_cvt_pk_bf16_f32 %0, %1, %2" : "=v"(r) : "v"(a), "v"(b));
    return r;
}

// ---------------- fp32 -> bf16 cast ----------------
__global__ __launch_bounds__(256) void cast_k(const float* __restrict__ in,
                                              unsigned short* __restrict__ out, long n) {
    long i = ((long)blockIdx.x * 256 + threadIdx.x) * 4;
    if (i >= n) return;
    float4 v = *(const float4*)(in + i);
    union { unsigned short h[4]; uint2 u; } c;
    c.h[0] = bf16bits(v.x); c.h[1] = bf16bits(v.y);
    c.h[2] = bf16bits(v.z); c.h[3] = bf16bits(v.w);
    *(uint2*)(out + i) = c.u;
}

// ---------------- RoPE tables ----------------
__global__ void rope_table_k(const int* __restrict__ pos,
                             float* __restrict__ cosT, float* __restrict__ sinT) {
    int s = blockIdx.x;
    int d = threadIdx.x;
    float p = (float)pos[s];
    float inv = powf(10000.0f, -(float)(2 * d) / 128.0f);
    float ang = p * inv;
    cosT[s * 64 + d] = cosf(ang);
    sinT[s * 64 + d] = sinf(ang);
}

// ---------------- RoPE apply in-place on bf16 [M, nh*128], with output scale ----------------
__global__ void rope_bf_k(unsigned short* __restrict__ x,
                          const float* __restrict__ cosT, const float* __restrict__ sinT,
                          int nh, float mul) {
    int idx = blockIdx.x * 256 + threadIdx.x;
    int d = idx & 63;
    int rest = idx >> 6;
    int h = rest % nh;
    int row = rest / nh;
    int s = row & (SLEN - 1);
    float c  = cosT[s * 64 + d] * mul;
    float sn = sinT[s * 64 + d] * mul;
    unsigned short* base = x + (size_t)row * (nh * HD) + h * HD;
    float x1 = bf2f(base[d]), x2 = bf2f(base[d + 64]);
    base[d]      = bf16bits(x1 * c - x2 * sn);
    base[d + 64] = bf16bits(x2 * c + x1 * sn);
}

// ---------------- V transpose: bf16 [M][KVDIM] -> bf16 Vt[b*KVH+kvh][d=128][s=2048] ----------------
__global__ __launch_bounds__(256) void vtrans_k(const unsigned short* __restrict__ V,
                                                unsigned short* __restrict__ Vt) {
    __shared__ unsigned short L[64][144];
    const int t = threadIdx.x;
    const int s0 = blockIdx.x * 64;
    const int bk = blockIdx.y;              // b*KVH + kvh
    const int b = bk >> 3, kvh = bk & 7;
    #pragma unroll
    for (int j = 0; j < 4; ++j) {
        int idx = t + j * 256;
        int row = idx >> 4;
        int c8  = (idx & 15) * 8;
        *(short8*)&L[row][c8] =
            *(const short8*)(V + ((size_t)b * SLEN + s0 + row) * KVDIM + kvh * HD + c8);
    }
    __syncthreads();
    {
        int d  = t >> 1;
        int sh = (t & 1) * 32;
        unsigned short tmp[32];
        #pragma unroll
        for (int j = 0; j < 32; ++j) tmp[j] = L[sh + j][d];
        unsigned short* dst = Vt + ((size_t)bk * HD + d) * SLEN + s0 + sh;
        #pragma unroll
        for (int j = 0; j < 4; ++j)
            *(short8*)(dst + j * 8) = *(const short8*)(tmp + j * 8);
    }
}

// ---------------- bf16 MFMA GEMM-NT (m97 structure); CT = float or ushort(bf16) out ----------------
template<typename CT>
__global__ __launch_bounds__(256) void gemm_bf16_nt(
    const unsigned short* __restrict__ A,
    const unsigned short* __restrict__ W,
    CT* __restrict__ C,
    int M, int N, int K)
{
    __shared__ unsigned short As[128 * 32];
    __shared__ unsigned short Bs[128 * 32];
    const int t    = threadIdx.x;
    const int wid  = t >> 6;
    const int lane = t & 63;
    const int m0 = blockIdx.y * 128, n0 = blockIdx.x * 128;
    const int wm = (wid >> 1) * 64, wn = (wid & 1) * 64;

    f32x4 acc[4][4];
    #pragma unroll
    for (int i = 0; i < 4; ++i)
        #pragma unroll
        for (int j = 0; j < 4; ++j)
            acc[i][j] = (f32x4){0.f, 0.f, 0.f, 0.f};

    const int srow  = wid * 16 + (lane >> 2);
    const int skcol = (lane & 3) * 8;
    const unsigned short* Abase = A + (size_t)(m0 + srow) * K + skcol;
    const unsigned short* Wbase = W + (size_t)(n0 + srow) * K + skcol;
    unsigned short* AsB = As + wid * 512;
    unsigned short* BsB = Bs + wid * 512;

    const int frow = lane & 15;
    const int fk   = (lane >> 4) * 8;

    for (int k0 = 0; k0 < K; k0 += 32) {
        __syncthreads();
        GLDS16(Abase + k0,                   AsB);
        GLDS16(Abase + (size_t)64 * K + k0,  AsB + 2048);
        GLDS16(Wbase + k0,                   BsB);
        GLDS16(Wbase + (size_t)64 * K + k0,  BsB + 2048);
        __syncthreads();

        short8 af[4], bfv[4];
        #pragma unroll
        for (int i = 0; i < 4; ++i)
            af[i] = *(const short8*)&As[(wm + i * 16 + frow) * 32 + fk];
        #pragma unroll
        for (int j = 0; j < 4; ++j)
            bfv[j] = *(const short8*)&Bs[(wn + j * 16 + frow) * 32 + fk];
        #pragma unroll
        for (int i = 0; i < 4; ++i)
            #pragma unroll
            for (int j = 0; j < 4; ++j)
                acc[i][j] = __builtin_amdgcn_mfma_f32_16x16x32_bf16(af[i], bfv[j], acc[i][j], 0, 0, 0);
    }

    const int crow = (lane >> 4) * 4, ccol = lane & 15;
    #pragma unroll
    for (int i = 0; i < 4; ++i)
        #pragma unroll
        for (int j = 0; j < 4; ++j) {
            CT* cp = C + (size_t)(m0 + wm + i * 16 + crow) * N + (n0 + wn + j * 16 + ccol);
            #pragma unroll
            for (int r = 0; r < 4; ++r) {
                if constexpr (sizeof(CT) == 2)
                    cp[(size_t)r * N] = bf16bits(acc[i][j][r]);
                else
                    cp[(size_t)r * N] = acc[i][j][r];
            }
        }
}

// ---------------- MFMA flash attention: swapped 32x32x16, in-register softmax ----------------
// grid (16, 64), 256 threads = 4 waves, wave handles 32 q-rows; KV tile = 64.
// No LDS, no barriers. Lane l owns q = l&31 (lanes l, l+32 hold kv/d halves).
// Q pre-scaled by (1/sqrt(128))*log2(e); softmax in exp2 domain; defer-max THR=8.
__global__ __launch_bounds__(256, 3) void flash_mfma32(
    const unsigned short* __restrict__ Qb,   // [MROWS][DMODEL] bf16 (rope'd, pre-scaled)
    const unsigned short* __restrict__ Kb,   // [MROWS][KVDIM] bf16 (rope'd)
    const unsigned short* __restrict__ Vt,   // [B*KVH][HD][SLEN] bf16
    unsigned short* __restrict__ Ob)         // [MROWS][DMODEL] bf16
{
    const int t = threadIdx.x;
    const int wid = t >> 6, lane = t & 63;
    const int qt = (int)gridDim.x - 1 - (int)blockIdx.x;   // heavy blocks first
    const int bh = blockIdx.y;
    const int b = bh >> 5, h = bh & 31, kvh = h >> 2;
    const int lq = lane & 31;        // this lane's q-row (local)
    const int hl = lane >> 5;        // half index
    const int qw0 = qt * 128 + wid * 32;
    const int qg = qw0 + lq;         // q position within sequence
    const size_t qrowg = (size_t)b * SLEN + qg;

    // ---- Q fragments (B-operand of QK^T): lane holds Q[qg][dt*16 + hl*8 .. +7]
    short8 qf[8];
    {
        const unsigned short* qp = Qb + qrowg * DMODEL + h * HD + hl * 8;
        #pragma unroll
        for (int dt = 0; dt < 8; ++dt)
            qf[dt] = *(const short8*)(qp + dt * 16);
    }

    // per-lane base pointers
    const unsigned short* Kl = Kb + ((size_t)b * SLEN + lq) * KVDIM + kvh * HD + hl * 8;
    const unsigned short* Vl = Vt + ((size_t)(b * KVHEADS + kvh) * HD + lq) * SLEN + hl * 8;

    f32x16 accO[4];
    #pragma unroll
    for (int db = 0; db < 4; ++db)
        #pragma unroll
        for (int r = 0; r < 16; ++r) accO[db][r] = 0.f;
    float m_i = -INFINITY, l_i = 0.f;

    const int nt = ((qw0 + 31) >> 6) + 1;   // causal tile count for this wave
    for (int kt = 0; kt < nt; ++kt) {
        // ---- QK^T: S^T[kv 64][q 32], two 32-kv blocks, 16 MFMA
        f32x16 sc[2];
        #pragma unroll
        for (int blk = 0; blk < 2; ++blk) {
            #pragma unroll
            for (int r = 0; r < 16; ++r) sc[blk][r] = 0.f;
            const unsigned short* kp = Kl + (size_t)(kt * 64 + blk * 32) * KVDIM;
            __builtin_amdgcn_s_setprio(1);
            #pragma unroll
            for (int dt = 0; dt < 8; ++dt) {
                short8 kf = *(const short8*)(kp + dt * 16);
                sc[blk] = __builtin_amdgcn_mfma_f32_32x32x16_bf16(kf, qf[dt], sc[blk], 0, 0, 0);
            }
            __builtin_amdgcn_s_setprio(0);
        }

        // ---- causal mask (only last tile)
        if (kt == nt - 1) {
            #pragma unroll
            for (int blk = 0; blk < 2; ++blk)
                #pragma unroll
                for (int r = 0; r < 16; ++r) {
                    int kv = kt * 64 + blk * 32 + (r & 3) + 8 * (r >> 2) + 4 * hl;
                    if (kv > qg) sc[blk][r] = -INFINITY;
                }
        }

        // ---- row max: in-lane over 32 + one cross-half swap
        float pmax = sc[0][0];
        #pragma unroll
        for (int r = 1; r < 16; ++r) pmax = fmaxf(pmax, sc[0][r]);
        #pragma unroll
        for (int r = 0; r < 16; ++r) pmax = fmaxf(pmax, sc[1][r]);
        {
            i32x2 mr = __builtin_amdgcn_permlane32_swap(__float_as_int(pmax), __float_as_int(pmax), false, false);
            pmax = fmaxf(__int_as_float(mr.x), __int_as_float(mr.y));
        }

        // ---- defer-max rescale (THR=8 in log2 domain -> P <= 256)
        if (!__all(pmax <= m_i + 8.0f)) {
            float mn = fmaxf(m_i, pmax);
            float al = exp2f(m_i - mn);
            m_i = mn;
            l_i *= al;
            #pragma unroll
            for (int db = 0; db < 4; ++db)
                #pragma unroll
                for (int r = 0; r < 16; ++r) accO[db][r] *= al;
        }

        // ---- exp + row sum
        float rs = 0.f;
        #pragma unroll
        for (int blk = 0; blk < 2; ++blk)
            #pragma unroll
            for (int r = 0; r < 16; ++r) {
                float pv = exp2f(sc[blk][r] - m_i);
                sc[blk][r] = pv;
                rs += pv;
            }
        {
            i32x2 sr = __builtin_amdgcn_permlane32_swap(__float_as_int(rs), __float_as_int(rs), false, false);
            rs = __int_as_float(sr.x) + __int_as_float(sr.y);
        }
        l_i += rs;

        // ---- pack P -> PV B-fragments, fully in registers (cvt_pk + permlane32_swap)
        // Lane (q, hl) needs kv = ks*16 + hl*8 + j. Own regs hold kv (r&3)+8*(r>>2)+4*hl;
        // partner lane (same q, hl^1) holds the complement. swap(x, y):
        //   ret.x = {lo: x_own, hi: y from lane-32}; ret.y = {lo: x from lane+32, hi: y_own}.
        short8 pf[4];   // kv slices 0..15,16..31,32..47,48..63 (16 each)
        #pragma unroll
        for (int blk = 0; blk < 2; ++blk) {
            unsigned c01 = cvtpk(sc[blk][0],  sc[blk][1]);   // kv {0,1}+4hl (+blk*32)
            unsigned c23 = cvtpk(sc[blk][2],  sc[blk][3]);   // kv {2,3}+4hl
            unsigned c45 = cvtpk(sc[blk][4],  sc[blk][5]);   // kv {8,9}+4hl
            unsigned c67 = cvtpk(sc[blk][6],  sc[blk][7]);   // kv {10,11}+4hl
            i32x2 sA = __builtin_amdgcn_permlane32_swap((int)c01, (int)c45, false, false);
            i32x2 sB = __builtin_amdgcn_permlane32_swap((int)c23, (int)c67, false, false);
            u32x4 f0 = {(unsigned)sA.x, (unsigned)sB.x, (unsigned)sA.y, (unsigned)sB.y};
            pf[blk * 2] = *(short8*)&f0;
            unsigned c89 = cvtpk(sc[blk][8],  sc[blk][9]);   // kv {16,17}+4hl
            unsigned cab = cvtpk(sc[blk][10], sc[blk][11]);  // kv {18,19}+4hl
            unsigned ccd = cvtpk(sc[blk][12], sc[blk][13]);  // kv {24,25}+4hl
            unsigned cef = cvtpk(sc[blk][14], sc[blk][15]);  // kv {26,27}+4hl
            i32x2 sC = __builtin_amdgcn_permlane32_swap((int)c89, (int)ccd, false, false);
            i32x2 sD = __builtin_amdgcn_permlane32_swap((int)cab, (int)cef, false, false);
            u32x4 f1 = {(unsigned)sC.x, (unsigned)sD.x, (unsigned)sC.y, (unsigned)sD.y};
            pf[blk * 2 + 1] = *(short8*)&f1;
        }

        // ---- PV: O^T[d][q] accum, A=V^T frag, B=P^T frag; 16 MFMA
        #pragma unroll
        for (int db = 0; db < 4; ++db) {
            const unsigned short* vp = Vl + (size_t)db * 32 * SLEN + kt * 64;
            __builtin_amdgcn_s_setprio(1);
            #pragma unroll
            for (int ks = 0; ks < 4; ++ks) {
                short8 vf = *(const short8*)(vp + ks * 16);
                accO[db] = __builtin_amdgcn_mfma_f32_32x32x16_bf16(vf, pf[ks], accO[db], 0, 0, 0);
            }
            __builtin_amdgcn_s_setprio(0);
        }
    }

    // ---- epilogue: normalize in-lane, pack 4xbf16 -> 8B stores
    float inv = 1.0f / l_i;
    unsigned short* orow = Ob + qrowg * DMODEL + h * HD;
    #pragma unroll
    for (int db = 0; db < 4; ++db)
        #pragma unroll
        for (int rq = 0; rq < 4; ++rq) {
            unsigned w0 = cvtpk(accO[db][rq * 4 + 0] * inv, accO[db][rq * 4 + 1] * inv);
            unsigned w1 = cvtpk(accO[db][rq * 4 + 2] * inv, accO[db][rq * 4 + 3] * inv);
            uint2 pkd; pkd.x = w0; pkd.y = w1;
            *(uint2*)(orow + db * 32 + rq * 8 + hl * 4) = pkd;
        }
}

extern "C" void kernel_launch(void* const* d_in, const int* in_sizes, int n_in,
                              void* d_out, int out_size, void* d_ws, size_t ws_size,
                              hipStream_t stream) {
    const float* hs  = (const float*)d_in[0];
    const int*   pos = (const int*)d_in[1];
    const float* wq  = (const float*)d_in[2];
    const float* wk  = (const float*)d_in[3];
    const float* wv  = (const float*)d_in[4];
    const float* wo  = (const float*)d_in[5];
    float* out = (float*)d_out;

    char* ws = (char*)d_ws;
    unsigned short* hs_bf  = (unsigned short*)(ws);                       // 32 MB
    unsigned short* wqo_bf = (unsigned short*)(ws + ((size_t)32  << 20)); // 32 MB (wq then wo)
    unsigned short* wk_bf  = (unsigned short*)(ws + ((size_t)64  << 20)); // 8 MB
    unsigned short* wv_bf  = (unsigned short*)(ws + ((size_t)72  << 20)); // 8 MB
    unsigned short* Qbf    = (unsigned short*)(ws + ((size_t)80  << 20)); // 32 MB
    unsigned short* Kbf    = (unsigned short*)(ws + ((size_t)112 << 20)); // 8 MB
    unsigned short* Vbf    = (unsigned short*)(ws + ((size_t)120 << 20)); // 8 MB
    unsigned short* Vtb    = (unsigned short*)(ws + ((size_t)128 << 20)); // 8 MB
    unsigned short* Obf    = (unsigned short*)(ws + ((size_t)136 << 20)); // 32 MB
    float*          cosT   = (float*)(ws + ((size_t)168 << 20));          // 512 KB
    float*          sinT   = (float*)(ws + ((size_t)168 << 20) + (size_t)SLEN * 64 * 4);

    const long nHS = (long)MROWS * DMODEL;
    const long nWQ = (long)DMODEL * DMODEL;
    const long nWK = (long)KVDIM * DMODEL;

    rope_table_k<<<SLEN, 64, 0, stream>>>(pos, cosT, sinT);

    cast_k<<<nHS / 4 / 256, 256, 0, stream>>>(hs, hs_bf, nHS);
    cast_k<<<nWQ / 4 / 256, 256, 0, stream>>>(wq, wqo_bf, nWQ);
    cast_k<<<nWK / 4 / 256, 256, 0, stream>>>(wk, wk_bf, nWK);
    cast_k<<<nWK / 4 / 256, 256, 0, stream>>>(wv, wv_bf, nWK);

    dim3 blk(256);
    gemm_bf16_nt<unsigned short><<<dim3(DMODEL/128, MROWS/128), blk, 0, stream>>>(hs_bf, wqo_bf, Qbf, MROWS, DMODEL, DMODEL);
    cast_k<<<nWQ / 4 / 256, 256, 0, stream>>>(wo, wqo_bf, nWQ);
    gemm_bf16_nt<unsigned short><<<dim3(KVDIM/128,  MROWS/128), blk, 0, stream>>>(hs_bf, wk_bf, Kbf, MROWS, KVDIM, DMODEL);
    gemm_bf16_nt<unsigned short><<<dim3(KVDIM/128,  MROWS/128), blk, 0, stream>>>(hs_bf, wv_bf, Vbf, MROWS, KVDIM, DMODEL);

    // Q gets (1/sqrt(128)) * log2(e) folded in; K unscaled
    const float qmul = 0.088388347648318447f * 1.4426950408889634f;
    rope_bf_k<<<(MROWS * NHEADS  * 64) / 256, 256, 0, stream>>>(Qbf, cosT, sinT, NHEADS, qmul);
    rope_bf_k<<<(MROWS * KVHEADS * 64) / 256, 256, 0, stream>>>(Kbf, cosT, sinT, KVHEADS, 1.0f);
    vtrans_k<<<dim3(SLEN/64, BATCH*KVHEADS), blk, 0, stream>>>(Vbf, Vtb);

    flash_mfma32<<<dim3(SLEN/128, BATCH*NHEADS), blk, 0, stream>>>(Qbf, Kbf, Vtb, Obf);

    gemm_bf16_nt<float><<<dim3(DMODEL/128, MROWS/128), blk, 0, stream>>>(Obf, wqo_bf, out, MROWS, DMODEL, DMODEL);
}

// Round 8
// 813.607 us; speedup vs baseline: 1.4008x; 1.4008x over previous
//
#include <hip/hip_runtime.h>
#include <hip/hip_bf16.h>
#include <math.h>

typedef __attribute__((ext_vector_type(8))) short short8;
typedef __attribute__((ext_vector_type(4))) float f32x4;
typedef __attribute__((ext_vector_type(16))) float f32x16;
typedef __attribute__((ext_vector_type(4))) unsigned int u32x4;
typedef __attribute__((ext_vector_type(2))) int i32x2;

#define BATCH   2
#define SLEN    2048
#define DMODEL  4096
#define NHEADS  32
#define KVHEADS 8
#define HD      128
#define KVDIM   (KVHEADS*HD)   // 1024
#define MROWS   (BATCH*SLEN)   // 4096

// async global->LDS, 16B per lane, dest = wave-uniform base + lane*16
#define GLDS16(gp, lp) __builtin_amdgcn_global_load_lds( \
    (const __attribute__((address_space(1))) void*)(gp), \
    (__attribute__((address_space(3))) void*)(lp), 16, 0, 0)

static __device__ __forceinline__ unsigned short bf16bits(float x) {
    __hip_bfloat16 h = __float2bfloat16(x);
    return *(unsigned short*)&h;
}
static __device__ __forceinline__ float bf2f(unsigned short u) {
    __hip_bfloat16 h = *(__hip_bfloat16*)&u;
    return __bfloat162float(h);
}
// v_cvt_pk_bf16_f32: lo=src0, hi=src1 (no builtin on gfx950)
static __device__ __forceinline__ unsigned cvtpk(float a, float b) {
    unsigned r;
    asm("v_cvt_pk_bf16_f32 %0, %1, %2" : "=v"(r) : "v"(a), "v"(b));
    return r;
}

// ---------------- fp32 -> bf16 cast ----------------
__global__ __launch_bounds__(256) void cast_k(const float* __restrict__ in,
                                              unsigned short* __restrict__ out, long n) {
    long i = ((long)blockIdx.x * 256 + threadIdx.x) * 4;
    if (i >= n) return;
    float4 v = *(const float4*)(in + i);
    union { unsigned short h[4]; uint2 u; } c;
    c.h[0] = bf16bits(v.x); c.h[1] = bf16bits(v.y);
    c.h[2] = bf16bits(v.z); c.h[3] = bf16bits(v.w);
    *(uint2*)(out + i) = c.u;
}

// ---------------- RoPE tables ----------------
__global__ void rope_table_k(const int* __restrict__ pos,
                             float* __restrict__ cosT, float* __restrict__ sinT) {
    int s = blockIdx.x;
    int d = threadIdx.x;
    float p = (float)pos[s];
    float inv = powf(10000.0f, -(float)(2 * d) / 128.0f);
    float ang = p * inv;
    cosT[s * 64 + d] = cosf(ang);
    sinT[s * 64 + d] = sinf(ang);
}

// ---------------- RoPE apply in-place on bf16 [M, nh*128], with output scale ----------------
__global__ void rope_bf_k(unsigned short* __restrict__ x,
                          const float* __restrict__ cosT, const float* __restrict__ sinT,
                          int nh, float mul) {
    int idx = blockIdx.x * 256 + threadIdx.x;
    int d = idx & 63;
    int rest = idx >> 6;
    int h = rest % nh;
    int row = rest / nh;
    int s = row & (SLEN - 1);
    float c  = cosT[s * 64 + d] * mul;
    float sn = sinT[s * 64 + d] * mul;
    unsigned short* base = x + (size_t)row * (nh * HD) + h * HD;
    float x1 = bf2f(base[d]), x2 = bf2f(base[d + 64]);
    base[d]      = bf16bits(x1 * c - x2 * sn);
    base[d + 64] = bf16bits(x2 * c + x1 * sn);
}

// ---------------- V transpose: bf16 [M][KVDIM] -> bf16 Vt[b*KVH+kvh][d=128][s=2048] ----------------
__global__ __launch_bounds__(256) void vtrans_k(const unsigned short* __restrict__ V,
                                                unsigned short* __restrict__ Vt) {
    __shared__ unsigned short L[64][144];
    const int t = threadIdx.x;
    const int s0 = blockIdx.x * 64;
    const int bk = blockIdx.y;              // b*KVH + kvh
    const int b = bk >> 3, kvh = bk & 7;
    #pragma unroll
    for (int j = 0; j < 4; ++j) {
        int idx = t + j * 256;
        int row = idx >> 4;
        int c8  = (idx & 15) * 8;
        *(short8*)&L[row][c8] =
            *(const short8*)(V + ((size_t)b * SLEN + s0 + row) * KVDIM + kvh * HD + c8);
    }
    __syncthreads();
    {
        int d  = t >> 1;
        int sh = (t & 1) * 32;
        unsigned short tmp[32];
        #pragma unroll
        for (int j = 0; j < 32; ++j) tmp[j] = L[sh + j][d];
        unsigned short* dst = Vt + ((size_t)bk * HD + d) * SLEN + s0 + sh;
        #pragma unroll
        for (int j = 0; j < 4; ++j)
            *(short8*)(dst + j * 8) = *(const short8*)(tmp + j * 8);
    }
}

// ---------------- bf16 MFMA GEMM-NT (m97 structure); CT = float or ushort(bf16) out ----------------
template<typename CT>
__global__ __launch_bounds__(256) void gemm_bf16_nt(
    const unsigned short* __restrict__ A,
    const unsigned short* __restrict__ W,
    CT* __restrict__ C,
    int M, int N, int K)
{
    __shared__ unsigned short As[128 * 32];
    __shared__ unsigned short Bs[128 * 32];
    const int t    = threadIdx.x;
    const int wid  = t >> 6;
    const int lane = t & 63;
    const int m0 = blockIdx.y * 128, n0 = blockIdx.x * 128;
    const int wm = (wid >> 1) * 64, wn = (wid & 1) * 64;

    f32x4 acc[4][4];
    #pragma unroll
    for (int i = 0; i < 4; ++i)
        #pragma unroll
        for (int j = 0; j < 4; ++j)
            acc[i][j] = (f32x4){0.f, 0.f, 0.f, 0.f};

    const int srow  = wid * 16 + (lane >> 2);
    const int skcol = (lane & 3) * 8;
    const unsigned short* Abase = A + (size_t)(m0 + srow) * K + skcol;
    const unsigned short* Wbase = W + (size_t)(n0 + srow) * K + skcol;
    unsigned short* AsB = As + wid * 512;
    unsigned short* BsB = Bs + wid * 512;

    const int frow = lane & 15;
    const int fk   = (lane >> 4) * 8;

    for (int k0 = 0; k0 < K; k0 += 32) {
        __syncthreads();
        GLDS16(Abase + k0,                   AsB);
        GLDS16(Abase + (size_t)64 * K + k0,  AsB + 2048);
        GLDS16(Wbase + k0,                   BsB);
        GLDS16(Wbase + (size_t)64 * K + k0,  BsB + 2048);
        __syncthreads();

        short8 af[4], bfv[4];
        #pragma unroll
        for (int i = 0; i < 4; ++i)
            af[i] = *(const short8*)&As[(wm + i * 16 + frow) * 32 + fk];
        #pragma unroll
        for (int j = 0; j < 4; ++j)
            bfv[j] = *(const short8*)&Bs[(wn + j * 16 + frow) * 32 + fk];
        #pragma unroll
        for (int i = 0; i < 4; ++i)
            #pragma unroll
            for (int j = 0; j < 4; ++j)
                acc[i][j] = __builtin_amdgcn_mfma_f32_16x16x32_bf16(af[i], bfv[j], acc[i][j], 0, 0, 0);
    }

    const int crow = (lane >> 4) * 4, ccol = lane & 15;
    #pragma unroll
    for (int i = 0; i < 4; ++i)
        #pragma unroll
        for (int j = 0; j < 4; ++j) {
            CT* cp = C + (size_t)(m0 + wm + i * 16 + crow) * N + (n0 + wn + j * 16 + ccol);
            #pragma unroll
            for (int r = 0; r < 4; ++r) {
                if constexpr (sizeof(CT) == 2)
                    cp[(size_t)r * N] = bf16bits(acc[i][j][r]);
                else
                    cp[(size_t)r * N] = acc[i][j][r];
            }
        }
}

// ---------------- MFMA flash attention: swapped 32x32x16, in-register softmax,
// LDS-shared double-buffered K/V with counted vmcnt (round-5 pipeline) ----------------
// grid (16, 64), 256 threads = 4 waves; wave w owns q rows qt*128+w*32..+31; KVBLK=64.
// Lane l owns q = l&31; hl = l>>5 indexes kv/d halves. Q pre-scaled by (1/sqrt(128))*log2(e).
__global__ __launch_bounds__(256, 2) void flash_mfma32(
    const unsigned short* __restrict__ Qb,   // [MROWS][DMODEL] bf16 (rope'd, pre-scaled)
    const unsigned short* __restrict__ Kb,   // [MROWS][KVDIM] bf16 (rope'd)
    const unsigned short* __restrict__ Vt,   // [B*KVH][HD][SLEN] bf16
    unsigned short* __restrict__ Ob)         // [MROWS][DMODEL] bf16
{
    __shared__ unsigned short Ks[2][64 * 128];   // [kv 64][d 128], rows 256B, swz (row&15)<<4
    __shared__ unsigned short Vs[2][128 * 64];   // [d 128][kv 64], rows 128B, swz (row&7)<<4

    const int t = threadIdx.x;
    const int wid = t >> 6, lane = t & 63;
    const int qt = (int)gridDim.x - 1 - (int)blockIdx.x;   // heavy blocks first
    const int bh = blockIdx.y;
    const int b = bh >> 5, h = bh & 31, kvh = h >> 2;
    const int lq = lane & 31;
    const int hl = lane >> 5;
    const int qw0 = qt * 128 + wid * 32;
    const int qg = qw0 + lq;
    const size_t qrowg = (size_t)b * SLEN + qg;

    const unsigned short* Kg0 = Kb + (size_t)b * SLEN * KVDIM + kvh * HD;
    const unsigned short* Vg0 = Vt + (size_t)(b * KVHEADS + kvh) * HD * SLEN;

    auto STAGE = [&](int buf, int kt) {   // 8 GLDS16 per thread
        const unsigned short* Kg = Kg0 + (size_t)kt * 64 * KVDIM;
        #pragma unroll
        for (int i = 0; i < 4; ++i) {
            int row = i * 16 + (t >> 4);
            int colel = ((((t & 15) << 4) ^ ((row & 15) << 4)) >> 1);
            GLDS16(Kg + (size_t)row * KVDIM + colel, &Ks[buf][i * 2048 + wid * 512]);
        }
        const unsigned short* Vg = Vg0 + kt * 64;
        #pragma unroll
        for (int i = 0; i < 4; ++i) {
            int row = i * 32 + (t >> 3);
            int colel = ((((t & 7) << 4) ^ ((row & 7) << 4)) >> 1);
            GLDS16(Vg + (size_t)row * SLEN + colel, &Vs[buf][i * 2048 + wid * 512]);
        }
    };

    // prologue: stage tile 0, then Q fragments to registers
    STAGE(0, 0);
    short8 qf[8];
    {
        const unsigned short* qp = Qb + qrowg * DMODEL + h * HD + hl * 8;
        #pragma unroll
        for (int dt = 0; dt < 8; ++dt)
            qf[dt] = *(const short8*)(qp + dt * 16);
    }

    f32x16 accO[4];
    #pragma unroll
    for (int db = 0; db < 4; ++db)
        #pragma unroll
        for (int r = 0; r < 16; ++r) accO[db][r] = 0.f;
    float m_i = -INFINITY, l_i = 0.f;

    const int ntmax = 2 * qt + 2;   // uniform across waves (waves 0,1: last tile fully masked)
    int p = 0;
    for (int kt = 0; kt < ntmax; ++kt) {
        if (kt + 1 < ntmax) {
            STAGE(p ^ 1, kt + 1);
            asm volatile("s_waitcnt vmcnt(8)" ::: "memory");   // prev tile's 8 loads landed
        } else {
            asm volatile("s_waitcnt vmcnt(0)" ::: "memory");
        }
        __builtin_amdgcn_s_barrier();
        __builtin_amdgcn_sched_barrier(0);

        const unsigned short* Kp = Ks[p];
        const unsigned short* Vp = Vs[p];

        // ---- QK^T: S^T[kv 64][q 32], 16 MFMA
        f32x16 sc[2];
        #pragma unroll
        for (int blk = 0; blk < 2; ++blk) {
            #pragma unroll
            for (int r = 0; r < 16; ++r) sc[blk][r] = 0.f;
            __builtin_amdgcn_s_setprio(1);
            #pragma unroll
            for (int dt = 0; dt < 8; ++dt) {
                int krow = blk * 32 + lq;
                int kb = krow * 256 + ((dt * 32 + hl * 16) ^ ((krow & 15) << 4));
                short8 kf = *(const short8*)(Kp + (kb >> 1));
                sc[blk] = __builtin_amdgcn_mfma_f32_32x32x16_bf16(kf, qf[dt], sc[blk], 0, 0, 0);
            }
            __builtin_amdgcn_s_setprio(0);
        }

        // ---- causal mask (only tiles that cross the diagonal for this wave)
        if (kt * 64 + 63 > qw0) {
            #pragma unroll
            for (int blk = 0; blk < 2; ++blk)
                #pragma unroll
                for (int r = 0; r < 16; ++r) {
                    int kv = kt * 64 + blk * 32 + (r & 3) + 8 * (r >> 2) + 4 * hl;
                    if (kv > qg) sc[blk][r] = -INFINITY;
                }
        }

        // ---- row max: in-lane over 32 + one cross-half swap
        float pmax = sc[0][0];
        #pragma unroll
        for (int r = 1; r < 16; ++r) pmax = fmaxf(pmax, sc[0][r]);
        #pragma unroll
        for (int r = 0; r < 16; ++r) pmax = fmaxf(pmax, sc[1][r]);
        {
            i32x2 mr = __builtin_amdgcn_permlane32_swap(__float_as_int(pmax), __float_as_int(pmax), false, false);
            pmax = fmaxf(__int_as_float(mr.x), __int_as_float(mr.y));
        }

        // ---- defer-max rescale (THR=8 in log2 domain -> P <= 256)
        if (!__all(pmax <= m_i + 8.0f)) {
            float mn = fmaxf(m_i, pmax);
            float al = exp2f(m_i - mn);
            m_i = mn;
            l_i *= al;
            #pragma unroll
            for (int db = 0; db < 4; ++db)
                #pragma unroll
                for (int r = 0; r < 16; ++r) accO[db][r] *= al;
        }

        // ---- exp + row sum
        float rs = 0.f;
        #pragma unroll
        for (int blk = 0; blk < 2; ++blk)
            #pragma unroll
            for (int r = 0; r < 16; ++r) {
                float pv = exp2f(sc[blk][r] - m_i);
                sc[blk][r] = pv;
                rs += pv;
            }
        {
            i32x2 sr = __builtin_amdgcn_permlane32_swap(__float_as_int(rs), __float_as_int(rs), false, false);
            rs = __int_as_float(sr.x) + __int_as_float(sr.y);
        }
        l_i += rs;

        // ---- pack P -> PV B-fragments in registers (cvt_pk + permlane32_swap; verified r7)
        short8 pf[4];
        #pragma unroll
        for (int blk = 0; blk < 2; ++blk) {
            unsigned c01 = cvtpk(sc[blk][0],  sc[blk][1]);
            unsigned c23 = cvtpk(sc[blk][2],  sc[blk][3]);
            unsigned c45 = cvtpk(sc[blk][4],  sc[blk][5]);
            unsigned c67 = cvtpk(sc[blk][6],  sc[blk][7]);
            i32x2 sA = __builtin_amdgcn_permlane32_swap((int)c01, (int)c45, false, false);
            i32x2 sB = __builtin_amdgcn_permlane32_swap((int)c23, (int)c67, false, false);
            u32x4 f0 = {(unsigned)sA.x, (unsigned)sB.x, (unsigned)sA.y, (unsigned)sB.y};
            pf[blk * 2] = *(short8*)&f0;
            unsigned c89 = cvtpk(sc[blk][8],  sc[blk][9]);
            unsigned cab = cvtpk(sc[blk][10], sc[blk][11]);
            unsigned ccd = cvtpk(sc[blk][12], sc[blk][13]);
            unsigned cef = cvtpk(sc[blk][14], sc[blk][15]);
            i32x2 sC = __builtin_amdgcn_permlane32_swap((int)c89, (int)ccd, false, false);
            i32x2 sD = __builtin_amdgcn_permlane32_swap((int)cab, (int)cef, false, false);
            u32x4 f1 = {(unsigned)sC.x, (unsigned)sD.x, (unsigned)sC.y, (unsigned)sD.y};
            pf[blk * 2 + 1] = *(short8*)&f1;
        }

        // ---- PV: O^T[d][q] accum, A=V^T frag from LDS; 16 MFMA
        #pragma unroll
        for (int db = 0; db < 4; ++db) {
            __builtin_amdgcn_s_setprio(1);
            #pragma unroll
            for (int ks = 0; ks < 4; ++ks) {
                int vrow = db * 32 + lq;
                int vb = vrow * 128 + ((ks * 32 + hl * 16) ^ ((vrow & 7) << 4));
                short8 vf = *(const short8*)(Vp + (vb >> 1));
                accO[db] = __builtin_amdgcn_mfma_f32_32x32x16_bf16(vf, pf[ks], accO[db], 0, 0, 0);
            }
            __builtin_amdgcn_s_setprio(0);
        }

        __builtin_amdgcn_sched_barrier(0);
        __builtin_amdgcn_s_barrier();   // all waves done reading buf p
        p ^= 1;
    }

    // ---- epilogue: normalize in-lane, pack 4xbf16 -> 8B stores
    float inv = 1.0f / l_i;
    unsigned short* orow = Ob + qrowg * DMODEL + h * HD;
    #pragma unroll
    for (int db = 0; db < 4; ++db)
        #pragma unroll
        for (int rq = 0; rq < 4; ++rq) {
            unsigned w0 = cvtpk(accO[db][rq * 4 + 0] * inv, accO[db][rq * 4 + 1] * inv);
            unsigned w1 = cvtpk(accO[db][rq * 4 + 2] * inv, accO[db][rq * 4 + 3] * inv);
            uint2 pkd; pkd.x = w0; pkd.y = w1;
            *(uint2*)(orow + db * 32 + rq * 8 + hl * 4) = pkd;
        }
}

extern "C" void kernel_launch(void* const* d_in, const int* in_sizes, int n_in,
                              void* d_out, int out_size, void* d_ws, size_t ws_size,
                              hipStream_t stream) {
    const float* hs  = (const float*)d_in[0];
    const int*   pos = (const int*)d_in[1];
    const float* wq  = (const float*)d_in[2];
    const float* wk  = (const float*)d_in[3];
    const float* wv  = (const float*)d_in[4];
    const float* wo  = (const float*)d_in[5];
    float* out = (float*)d_out;

    char* ws = (char*)d_ws;
    unsigned short* hs_bf  = (unsigned short*)(ws);                       // 32 MB
    unsigned short* wqo_bf = (unsigned short*)(ws + ((size_t)32  << 20)); // 32 MB (wq then wo)
    unsigned short* wk_bf  = (unsigned short*)(ws + ((size_t)64  << 20)); // 8 MB
    unsigned short* wv_bf  = (unsigned short*)(ws + ((size_t)72  << 20)); // 8 MB
    unsigned short* Qbf    = (unsigned short*)(ws + ((size_t)80  << 20)); // 32 MB
    unsigned short* Kbf    = (unsigned short*)(ws + ((size_t)112 << 20)); // 8 MB
    unsigned short* Vbf    = (unsigned short*)(ws + ((size_t)120 << 20)); // 8 MB
    unsigned short* Vtb    = (unsigned short*)(ws + ((size_t)128 << 20)); // 8 MB
    unsigned short* Obf    = (unsigned short*)(ws + ((size_t)136 << 20)); // 32 MB
    float*          cosT   = (float*)(ws + ((size_t)168 << 20));          // 512 KB
    float*          sinT   = (float*)(ws + ((size_t)168 << 20) + (size_t)SLEN * 64 * 4);

    const long nHS = (long)MROWS * DMODEL;
    const long nWQ = (long)DMODEL * DMODEL;
    const long nWK = (long)KVDIM * DMODEL;

    rope_table_k<<<SLEN, 64, 0, stream>>>(pos, cosT, sinT);

    cast_k<<<nHS / 4 / 256, 256, 0, stream>>>(hs, hs_bf, nHS);
    cast_k<<<nWQ / 4 / 256, 256, 0, stream>>>(wq, wqo_bf, nWQ);
    cast_k<<<nWK / 4 / 256, 256, 0, stream>>>(wk, wk_bf, nWK);
    cast_k<<<nWK / 4 / 256, 256, 0, stream>>>(wv, wv_bf, nWK);

    dim3 blk(256);
    gemm_bf16_nt<unsigned short><<<dim3(DMODEL/128, MROWS/128), blk, 0, stream>>>(hs_bf, wqo_bf, Qbf, MROWS, DMODEL, DMODEL);
    cast_k<<<nWQ / 4 / 256, 256, 0, stream>>>(wo, wqo_bf, nWQ);
    gemm_bf16_nt<unsigned short><<<dim3(KVDIM/128,  MROWS/128), blk, 0, stream>>>(hs_bf, wk_bf, Kbf, MROWS, KVDIM, DMODEL);
    gemm_bf16_nt<unsigned short><<<dim3(KVDIM/128,  MROWS/128), blk, 0, stream>>>(hs_bf, wv_bf, Vbf, MROWS, KVDIM, DMODEL);

    // Q gets (1/sqrt(128)) * log2(e) folded in; K unscaled
    const float qmul = 0.088388347648318447f * 1.4426950408889634f;
    rope_bf_k<<<(MROWS * NHEADS  * 64) / 256, 256, 0, stream>>>(Qbf, cosT, sinT, NHEADS, qmul);
    rope_bf_k<<<(MROWS * KVHEADS * 64) / 256, 256, 0, stream>>>(Kbf, cosT, sinT, KVHEADS, 1.0f);
    vtrans_k<<<dim3(SLEN/64, BATCH*KVHEADS), blk, 0, stream>>>(Vbf, Vtb);

    flash_mfma32<<<dim3(SLEN/128, BATCH*NHEADS), blk, 0, stream>>>(Qbf, Kbf, Vtb, Obf);

    gemm_bf16_nt<float><<<dim3(DMODEL/128, MROWS/128), blk, 0, stream>>>(Obf, wqo_bf, out, MROWS, DMODEL, DMODEL);
}

// Round 9
// 687.773 us; speedup vs baseline: 1.6571x; 1.1830x over previous
//
#include <hip/hip_runtime.h>
#include <hip/hip_bf16.h>
#include <math.h>

typedef __attribute__((ext_vector_type(8))) short short8;
typedef __attribute__((ext_vector_type(4))) float f32x4;
typedef __attribute__((ext_vector_type(16))) float f32x16;
typedef __attribute__((ext_vector_type(4))) unsigned int u32x4;
typedef __attribute__((ext_vector_type(2))) int i32x2;

#define BATCH   2
#define SLEN    2048
#define DMODEL  4096
#define NHEADS  32
#define KVHEADS 8
#define HD      128
#define KVDIM   (KVHEADS*HD)   // 1024
#define MROWS   (BATCH*SLEN)   // 4096
#define NQKV    (DMODEL + 2*KVDIM)   // 6144

// async global->LDS, 16B per lane, dest = wave-uniform base + lane*16
#define GLDS16(gp, lp) __builtin_amdgcn_global_load_lds( \
    (const __attribute__((address_space(1))) void*)(gp), \
    (__attribute__((address_space(3))) void*)(lp), 16, 0, 0)

static __device__ __forceinline__ unsigned short bf16bits(float x) {
    __hip_bfloat16 h = __float2bfloat16(x);
    return *(unsigned short*)&h;
}
static __device__ __forceinline__ float bf2f(unsigned short u) {
    __hip_bfloat16 h = *(__hip_bfloat16*)&u;
    return __bfloat162float(h);
}
// v_cvt_pk_bf16_f32: lo=src0, hi=src1 (no builtin on gfx950)
static __device__ __forceinline__ unsigned cvtpk(float a, float b) {
    unsigned r;
    asm("v_cvt_pk_bf16_f32 %0, %1, %2" : "=v"(r) : "v"(a), "v"(b));
    return r;
}

// ---------------- fp32 -> bf16 cast ----------------
__global__ __launch_bounds__(256) void cast_k(const float* __restrict__ in,
                                              unsigned short* __restrict__ out, long n) {
    long i = ((long)blockIdx.x * 256 + threadIdx.x) * 4;
    if (i >= n) return;
    float4 v = *(const float4*)(in + i);
    union { unsigned short h[4]; uint2 u; } c;
    c.h[0] = bf16bits(v.x); c.h[1] = bf16bits(v.y);
    c.h[2] = bf16bits(v.z); c.h[3] = bf16bits(v.w);
    *(uint2*)(out + i) = c.u;
}

// ---------------- RoPE tables ----------------
__global__ void rope_table_k(const int* __restrict__ pos,
                             float* __restrict__ cosT, float* __restrict__ sinT) {
    int s = blockIdx.x;
    int d = threadIdx.x;
    float p = (float)pos[s];
    float inv = powf(10000.0f, -(float)(2 * d) / 128.0f);
    float ang = p * inv;
    cosT[s * 64 + d] = cosf(ang);
    sinT[s * 64 + d] = sinf(ang);
}

// ---------------- RoPE apply in-place on bf16, row stride ld ----------------
__global__ void rope_bf_k(unsigned short* __restrict__ x,
                          const float* __restrict__ cosT, const float* __restrict__ sinT,
                          int nh, int ld, float mul) {
    int idx = blockIdx.x * 256 + threadIdx.x;
    int d = idx & 63;
    int rest = idx >> 6;
    int h = rest % nh;
    int row = rest / nh;
    int s = row & (SLEN - 1);
    float c  = cosT[s * 64 + d] * mul;
    float sn = sinT[s * 64 + d] * mul;
    unsigned short* base = x + (size_t)row * ld + h * HD;
    float x1 = bf2f(base[d]), x2 = bf2f(base[d + 64]);
    base[d]      = bf16bits(x1 * c - x2 * sn);
    base[d + 64] = bf16bits(x2 * c + x1 * sn);
}

// ---------------- V transpose: bf16 [M][ldv] -> bf16 Vt[b*KVH+kvh][d=128][s=2048] ----------------
__global__ __launch_bounds__(256) void vtrans_k(const unsigned short* __restrict__ V, int ldv,
                                                unsigned short* __restrict__ Vt) {
    __shared__ unsigned short L[64][144];
    const int t = threadIdx.x;
    const int s0 = blockIdx.x * 64;
    const int bk = blockIdx.y;              // b*KVH + kvh
    const int b = bk >> 3, kvh = bk & 7;
    #pragma unroll
    for (int j = 0; j < 4; ++j) {
        int idx = t + j * 256;
        int row = idx >> 4;
        int c8  = (idx & 15) * 8;
        *(short8*)&L[row][c8] =
            *(const short8*)(V + ((size_t)b * SLEN + s0 + row) * ldv + kvh * HD + c8);
    }
    __syncthreads();
    {
        int d  = t >> 1;
        int sh = (t & 1) * 32;
        unsigned short tmp[32];
        #pragma unroll
        for (int j = 0; j < 32; ++j) tmp[j] = L[sh + j][d];
        unsigned short* dst = Vt + ((size_t)bk * HD + d) * SLEN + s0 + sh;
        #pragma unroll
        for (int j = 0; j < 4; ++j)
            *(short8*)(dst + j * 8) = *(const short8*)(tmp + j * 8);
    }
}

// ---------------- 256x256 bf16 MFMA GEMM-NT, BK=64, 8 waves, counted-vmcnt dbuf ----------------
// C[M][ldc] = A[M][lda] * W[N][ldw]^T. LDS halves [128][64] with slot^=(row&7) XOR swizzle
// (pre-swizzled global source + swizzled ds_read; verified conflict-free in flash r8).
template<typename CT>
__global__ __launch_bounds__(512, 2) void gemm256(
    const unsigned short* __restrict__ A, int lda,
    const unsigned short* __restrict__ W, int ldw,
    CT* __restrict__ C, int ldc,
    int M, int N, int K)
{
    __shared__ unsigned short Asl[2][2][128 * 64];   // [buf][half][row*64 + col]
    __shared__ unsigned short Bsl[2][2][128 * 64];

    const int t = threadIdx.x;           // 0..511
    const int w = t >> 6, lane = t & 63;
    const int m0 = blockIdx.y * 256, n0 = blockIdx.x * 256;
    const int wm = (w >> 2) * 128;       // 0 / 128
    const int wn = (w & 3) * 64;         // 0,64,128,192
    const int fr = lane & 15, hi = lane >> 4;

    f32x4 acc[8][4];
    #pragma unroll
    for (int i = 0; i < 8; ++i)
        #pragma unroll
        for (int j = 0; j < 4; ++j)
            acc[i][j] = (f32x4){0.f, 0.f, 0.f, 0.f};

    // staging geometry: thread covers (row = j*64 + (t>>3), slot = t&7); dest linear in lane
    const int sr = t >> 3;               // w*8 + (lane>>3)
    const int sl = t & 7;

    auto STAGE = [&](int buf, int kt) {  // 8 GLDS16 per thread (A/B x half x j)
        const int k0 = kt * 64;
        #pragma unroll
        for (int half = 0; half < 2; ++half) {
            #pragma unroll
            for (int j = 0; j < 2; ++j) {
                int row  = j * 64 + sr;
                int scol = k0 + ((sl ^ (row & 7)) << 3);
                GLDS16(A + (size_t)(m0 + half * 128 + row) * lda + scol,
                       &Asl[buf][half][j * 4096 + w * 512]);
                GLDS16(W + (size_t)(n0 + half * 128 + row) * ldw + scol,
                       &Bsl[buf][half][j * 4096 + w * 512]);
            }
        }
    };

    STAGE(0, 0);
    const int NT = K >> 6;
    int buf = 0;
    for (int kt = 0; kt < NT; ++kt) {
        if (kt + 1 < NT) {
            STAGE(buf ^ 1, kt + 1);
            asm volatile("s_waitcnt vmcnt(8)" ::: "memory");   // this tile's 8 loads landed
        } else {
            asm volatile("s_waitcnt vmcnt(0)" ::: "memory");
        }
        __builtin_amdgcn_s_barrier();
        __builtin_amdgcn_sched_barrier(0);

        const unsigned short* Ah = Asl[buf][w >> 2];
        const unsigned short* Bh = Bsl[buf][wn >> 7];

        // B fragments for this wave's 64 cols (register-cached across all i)
        short8 bfr[4][2];
        #pragma unroll
        for (int j = 0; j < 4; ++j) {
            int lr = (wn & 127) + j * 16 + fr;
            int swz = lr & 7;
            #pragma unroll
            for (int kk = 0; kk < 2; ++kk) {
                int s0 = kk * 4 + hi;
                bfr[j][kk] = *(const short8*)&Bh[lr * 64 + ((s0 ^ swz) << 3)];
            }
        }
        #pragma unroll
        for (int i = 0; i < 8; ++i) {
            int lr = i * 16 + fr;
            int swz = lr & 7;
            short8 a0 = *(const short8*)&Ah[lr * 64 + (((0 + hi) ^ swz) << 3)];
            short8 a1 = *(const short8*)&Ah[lr * 64 + (((4 + hi) ^ swz) << 3)];
            __builtin_amdgcn_s_setprio(1);
            #pragma unroll
            for (int j = 0; j < 4; ++j) {
                acc[i][j] = __builtin_amdgcn_mfma_f32_16x16x32_bf16(a0, bfr[j][0], acc[i][j], 0, 0, 0);
                acc[i][j] = __builtin_amdgcn_mfma_f32_16x16x32_bf16(a1, bfr[j][1], acc[i][j], 0, 0, 0);
            }
            __builtin_amdgcn_s_setprio(0);
        }

        __builtin_amdgcn_sched_barrier(0);
        __builtin_amdgcn_s_barrier();    // all waves done reading buf
        buf ^= 1;
    }

    // epilogue: C/D layout col=lane&15, row=(lane>>4)*4+reg (verified)
    const int crow = (lane >> 4) * 4, ccol = lane & 15;
    #pragma unroll
    for (int i = 0; i < 8; ++i)
        #pragma unroll
        for (int j = 0; j < 4; ++j) {
            CT* cp = C + (size_t)(m0 + wm + i * 16 + crow) * ldc + (n0 + wn + j * 16 + ccol);
            #pragma unroll
            for (int r = 0; r < 4; ++r) {
                if constexpr (sizeof(CT) == 2)
                    cp[(size_t)r * ldc] = bf16bits(acc[i][j][r]);
                else
                    cp[(size_t)r * ldc] = acc[i][j][r];
            }
        }
}

// ---------------- MFMA flash attention: swapped 32x32x16, in-register softmax,
// LDS-shared double-buffered K/V with counted vmcnt (verified r8) ----------------
__global__ __launch_bounds__(256, 2) void flash_mfma32(
    const unsigned short* __restrict__ Qb, int ldq,   // rope'd, pre-scaled
    const unsigned short* __restrict__ Kb, int ldk,   // rope'd
    const unsigned short* __restrict__ Vt,            // [B*KVH][HD][SLEN]
    unsigned short* __restrict__ Ob)                  // [MROWS][DMODEL]
{
    __shared__ unsigned short Ks[2][64 * 128];   // [kv 64][d 128], rows 256B, swz (row&15)<<4
    __shared__ unsigned short Vs[2][128 * 64];   // [d 128][kv 64], rows 128B, swz (row&7)<<4

    const int t = threadIdx.x;
    const int wid = t >> 6, lane = t & 63;
    const int qt = (int)gridDim.x - 1 - (int)blockIdx.x;   // heavy blocks first
    const int bh = blockIdx.y;
    const int b = bh >> 5, h = bh & 31, kvh = h >> 2;
    const int lq = lane & 31;
    const int hl = lane >> 5;
    const int qw0 = qt * 128 + wid * 32;
    const int qg = qw0 + lq;
    const size_t qrowg = (size_t)b * SLEN + qg;

    const unsigned short* Kg0 = Kb + (size_t)b * SLEN * ldk + kvh * HD;
    const unsigned short* Vg0 = Vt + (size_t)(b * KVHEADS + kvh) * HD * SLEN;

    auto STAGE = [&](int buf, int kt) {   // 8 GLDS16 per thread
        const unsigned short* Kg = Kg0 + (size_t)kt * 64 * ldk;
        #pragma unroll
        for (int i = 0; i < 4; ++i) {
            int row = i * 16 + (t >> 4);
            int colel = ((((t & 15) << 4) ^ ((row & 15) << 4)) >> 1);
            GLDS16(Kg + (size_t)row * ldk + colel, &Ks[buf][i * 2048 + wid * 512]);
        }
        const unsigned short* Vg = Vg0 + kt * 64;
        #pragma unroll
        for (int i = 0; i < 4; ++i) {
            int row = i * 32 + (t >> 3);
            int colel = ((((t & 7) << 4) ^ ((row & 7) << 4)) >> 1);
            GLDS16(Vg + (size_t)row * SLEN + colel, &Vs[buf][i * 2048 + wid * 512]);
        }
    };

    STAGE(0, 0);
    short8 qf[8];
    {
        const unsigned short* qp = Qb + qrowg * ldq + h * HD + hl * 8;
        #pragma unroll
        for (int dt = 0; dt < 8; ++dt)
            qf[dt] = *(const short8*)(qp + dt * 16);
    }

    f32x16 accO[4];
    #pragma unroll
    for (int db = 0; db < 4; ++db)
        #pragma unroll
        for (int r = 0; r < 16; ++r) accO[db][r] = 0.f;
    float m_i = -INFINITY, l_i = 0.f;

    const int ntmax = 2 * qt + 2;   // uniform across waves
    int p = 0;
    for (int kt = 0; kt < ntmax; ++kt) {
        if (kt + 1 < ntmax) {
            STAGE(p ^ 1, kt + 1);
            asm volatile("s_waitcnt vmcnt(8)" ::: "memory");
        } else {
            asm volatile("s_waitcnt vmcnt(0)" ::: "memory");
        }
        __builtin_amdgcn_s_barrier();
        __builtin_amdgcn_sched_barrier(0);

        const unsigned short* Kp = Ks[p];
        const unsigned short* Vp = Vs[p];

        // ---- QK^T: S^T[kv 64][q 32], 16 MFMA
        f32x16 sc[2];
        #pragma unroll
        for (int blk = 0; blk < 2; ++blk) {
            #pragma unroll
            for (int r = 0; r < 16; ++r) sc[blk][r] = 0.f;
            __builtin_amdgcn_s_setprio(1);
            #pragma unroll
            for (int dt = 0; dt < 8; ++dt) {
                int krow = blk * 32 + lq;
                int kb = krow * 256 + ((dt * 32 + hl * 16) ^ ((krow & 15) << 4));
                short8 kf = *(const short8*)(Kp + (kb >> 1));
                sc[blk] = __builtin_amdgcn_mfma_f32_32x32x16_bf16(kf, qf[dt], sc[blk], 0, 0, 0);
            }
            __builtin_amdgcn_s_setprio(0);
        }

        // ---- causal mask
        if (kt * 64 + 63 > qw0) {
            #pragma unroll
            for (int blk = 0; blk < 2; ++blk)
                #pragma unroll
                for (int r = 0; r < 16; ++r) {
                    int kv = kt * 64 + blk * 32 + (r & 3) + 8 * (r >> 2) + 4 * hl;
                    if (kv > qg) sc[blk][r] = -INFINITY;
                }
        }

        // ---- row max (in-lane + one cross-half swap)
        float pmax = sc[0][0];
        #pragma unroll
        for (int r = 1; r < 16; ++r) pmax = fmaxf(pmax, sc[0][r]);
        #pragma unroll
        for (int r = 0; r < 16; ++r) pmax = fmaxf(pmax, sc[1][r]);
        {
            i32x2 mr = __builtin_amdgcn_permlane32_swap(__float_as_int(pmax), __float_as_int(pmax), false, false);
            pmax = fmaxf(__int_as_float(mr.x), __int_as_float(mr.y));
        }

        // ---- defer-max rescale (THR=8 log2 -> P<=256)
        if (!__all(pmax <= m_i + 8.0f)) {
            float mn = fmaxf(m_i, pmax);
            float al = exp2f(m_i - mn);
            m_i = mn;
            l_i *= al;
            #pragma unroll
            for (int db = 0; db < 4; ++db)
                #pragma unroll
                for (int r = 0; r < 16; ++r) accO[db][r] *= al;
        }

        // ---- exp + row sum
        float rs = 0.f;
        #pragma unroll
        for (int blk = 0; blk < 2; ++blk)
            #pragma unroll
            for (int r = 0; r < 16; ++r) {
                float pv = exp2f(sc[blk][r] - m_i);
                sc[blk][r] = pv;
                rs += pv;
            }
        {
            i32x2 sr = __builtin_amdgcn_permlane32_swap(__float_as_int(rs), __float_as_int(rs), false, false);
            rs = __int_as_float(sr.x) + __int_as_float(sr.y);
        }
        l_i += rs;

        // ---- pack P -> PV B-fragments in registers (verified r7)
        short8 pf[4];
        #pragma unroll
        for (int blk = 0; blk < 2; ++blk) {
            unsigned c01 = cvtpk(sc[blk][0],  sc[blk][1]);
            unsigned c23 = cvtpk(sc[blk][2],  sc[blk][3]);
            unsigned c45 = cvtpk(sc[blk][4],  sc[blk][5]);
            unsigned c67 = cvtpk(sc[blk][6],  sc[blk][7]);
            i32x2 sA = __builtin_amdgcn_permlane32_swap((int)c01, (int)c45, false, false);
            i32x2 sB = __builtin_amdgcn_permlane32_swap((int)c23, (int)c67, false, false);
            u32x4 f0 = {(unsigned)sA.x, (unsigned)sB.x, (unsigned)sA.y, (unsigned)sB.y};
            pf[blk * 2] = *(short8*)&f0;
            unsigned c89 = cvtpk(sc[blk][8],  sc[blk][9]);
            unsigned cab = cvtpk(sc[blk][10], sc[blk][11]);
            unsigned ccd = cvtpk(sc[blk][12], sc[blk][13]);
            unsigned cef = cvtpk(sc[blk][14], sc[blk][15]);
            i32x2 sC = __builtin_amdgcn_permlane32_swap((int)c89, (int)ccd, false, false);
            i32x2 sD = __builtin_amdgcn_permlane32_swap((int)cab, (int)cef, false, false);
            u32x4 f1 = {(unsigned)sC.x, (unsigned)sD.x, (unsigned)sC.y, (unsigned)sD.y};
            pf[blk * 2 + 1] = *(short8*)&f1;
        }

        // ---- PV: O^T[d][q] accum, 16 MFMA
        #pragma unroll
        for (int db = 0; db < 4; ++db) {
            __builtin_amdgcn_s_setprio(1);
            #pragma unroll
            for (int ks = 0; ks < 4; ++ks) {
                int vrow = db * 32 + lq;
                int vb = vrow * 128 + ((ks * 32 + hl * 16) ^ ((vrow & 7) << 4));
                short8 vf = *(const short8*)(Vp + (vb >> 1));
                accO[db] = __builtin_amdgcn_mfma_f32_32x32x16_bf16(vf, pf[ks], accO[db], 0, 0, 0);
            }
            __builtin_amdgcn_s_setprio(0);
        }

        __builtin_amdgcn_sched_barrier(0);
        __builtin_amdgcn_s_barrier();
        p ^= 1;
    }

    // ---- epilogue
    float inv = 1.0f / l_i;
    unsigned short* orow = Ob + qrowg * DMODEL + h * HD;
    #pragma unroll
    for (int db = 0; db < 4; ++db)
        #pragma unroll
        for (int rq = 0; rq < 4; ++rq) {
            unsigned w0 = cvtpk(accO[db][rq * 4 + 0] * inv, accO[db][rq * 4 + 1] * inv);
            unsigned w1 = cvtpk(accO[db][rq * 4 + 2] * inv, accO[db][rq * 4 + 3] * inv);
            uint2 pkd; pkd.x = w0; pkd.y = w1;
            *(uint2*)(orow + db * 32 + rq * 8 + hl * 4) = pkd;
        }
}

extern "C" void kernel_launch(void* const* d_in, const int* in_sizes, int n_in,
                              void* d_out, int out_size, void* d_ws, size_t ws_size,
                              hipStream_t stream) {
    const float* hs  = (const float*)d_in[0];
    const int*   pos = (const int*)d_in[1];
    const float* wq  = (const float*)d_in[2];
    const float* wk  = (const float*)d_in[3];
    const float* wv  = (const float*)d_in[4];
    const float* wo  = (const float*)d_in[5];
    float* out = (float*)d_out;

    char* ws = (char*)d_ws;
    unsigned short* hs_bf   = (unsigned short*)(ws);                        // 32 MB
    unsigned short* wqkv_bf = (unsigned short*)(ws + ((size_t)32  << 20));  // 48 MB [6144][4096]
    unsigned short* wo_bf   = (unsigned short*)(ws + ((size_t)80  << 20));  // 32 MB
    unsigned short* qkv_bf  = (unsigned short*)(ws + ((size_t)112 << 20));  // 48 MB [4096][6144]
    unsigned short* Vtb     = (unsigned short*)(ws + ((size_t)160 << 20));  // 8 MB
    unsigned short* Obf     = (unsigned short*)(ws + ((size_t)168 << 20));  // 32 MB
    float*          cosT    = (float*)(ws + ((size_t)200 << 20));           // 512 KB
    float*          sinT    = (float*)(ws + ((size_t)200 << 20) + (size_t)SLEN * 64 * 4);
    // total ~201 MB

    const long nHS = (long)MROWS * DMODEL;
    const long nWQ = (long)DMODEL * DMODEL;
    const long nWK = (long)KVDIM * DMODEL;

    rope_table_k<<<SLEN, 64, 0, stream>>>(pos, cosT, sinT);

    cast_k<<<nHS / 4 / 256, 256, 0, stream>>>(hs, hs_bf, nHS);
    cast_k<<<nWQ / 4 / 256, 256, 0, stream>>>(wq, wqkv_bf, nWQ);
    cast_k<<<nWK / 4 / 256, 256, 0, stream>>>(wk, wqkv_bf + (size_t)DMODEL * DMODEL, nWK);
    cast_k<<<nWK / 4 / 256, 256, 0, stream>>>(wv, wqkv_bf + (size_t)(DMODEL + KVDIM) * DMODEL, nWK);
    cast_k<<<nWQ / 4 / 256, 256, 0, stream>>>(wo, wo_bf, nWQ);

    // fused QKV projection: [4096][6144] bf16
    gemm256<unsigned short><<<dim3(NQKV/256, MROWS/256), 512, 0, stream>>>(
        hs_bf, DMODEL, wqkv_bf, DMODEL, qkv_bf, NQKV, MROWS, NQKV, DMODEL);

    // Q gets (1/sqrt(128)) * log2(e) folded in; K unscaled
    const float qmul = 0.088388347648318447f * 1.4426950408889634f;
    rope_bf_k<<<(MROWS * NHEADS  * 64) / 256, 256, 0, stream>>>(qkv_bf,          cosT, sinT, NHEADS,  NQKV, qmul);
    rope_bf_k<<<(MROWS * KVHEADS * 64) / 256, 256, 0, stream>>>(qkv_bf + DMODEL, cosT, sinT, KVHEADS, NQKV, 1.0f);
    vtrans_k<<<dim3(SLEN/64, BATCH*KVHEADS), 256, 0, stream>>>(qkv_bf + DMODEL + KVDIM, NQKV, Vtb);

    flash_mfma32<<<dim3(SLEN/128, BATCH*NHEADS), 256, 0, stream>>>(
        qkv_bf, NQKV, qkv_bf + DMODEL, NQKV, Vtb, Obf);

    gemm256<float><<<dim3(DMODEL/256, MROWS/256), 512, 0, stream>>>(
        Obf, DMODEL, wo_bf, DMODEL, out, DMODEL, MROWS, DMODEL, DMODEL);
}

// Round 10
// 635.639 us; speedup vs baseline: 1.7930x; 1.0820x over previous
//
#include <hip/hip_runtime.h>
#include <hip/hip_bf16.h>
#include <math.h>

typedef __attribute__((ext_vector_type(8))) short short8;
typedef __attribute__((ext_vector_type(4))) float f32x4;
typedef __attribute__((ext_vector_type(16))) float f32x16;
typedef __attribute__((ext_vector_type(4))) unsigned int u32x4;
typedef __attribute__((ext_vector_type(2))) int i32x2;

#define BATCH   2
#define SLEN    2048
#define DMODEL  4096
#define NHEADS  32
#define KVHEADS 8
#define HD      128
#define KVDIM   (KVHEADS*HD)   // 1024
#define MROWS   (BATCH*SLEN)   // 4096
#define NQKV    (DMODEL + 2*KVDIM)   // 6144

// async global->LDS, 16B per lane, dest = wave-uniform base + lane*16
#define GLDS16(gp, lp) __builtin_amdgcn_global_load_lds( \
    (const __attribute__((address_space(1))) void*)(gp), \
    (__attribute__((address_space(3))) void*)(lp), 16, 0, 0)

static __device__ __forceinline__ unsigned short bf16bits(float x) {
    __hip_bfloat16 h = __float2bfloat16(x);
    return *(unsigned short*)&h;
}
static __device__ __forceinline__ float bf2f(unsigned short u) {
    __hip_bfloat16 h = *(__hip_bfloat16*)&u;
    return __bfloat162float(h);
}
// v_cvt_pk_bf16_f32: lo=src0, hi=src1 (no builtin on gfx950)
static __device__ __forceinline__ unsigned cvtpk(float a, float b) {
    unsigned r;
    asm("v_cvt_pk_bf16_f32 %0, %1, %2" : "=v"(r) : "v"(a), "v"(b));
    return r;
}

// ---------------- fp32 -> bf16 cast ----------------
__global__ __launch_bounds__(256) void cast_k(const float* __restrict__ in,
                                              unsigned short* __restrict__ out, long n) {
    long i = ((long)blockIdx.x * 256 + threadIdx.x) * 4;
    if (i >= n) return;
    float4 v = *(const float4*)(in + i);
    union { unsigned short h[4]; uint2 u; } c;
    c.h[0] = bf16bits(v.x); c.h[1] = bf16bits(v.y);
    c.h[2] = bf16bits(v.z); c.h[3] = bf16bits(v.w);
    *(uint2*)(out + i) = c.u;
}

// ---------------- RoPE tables ----------------
__global__ void rope_table_k(const int* __restrict__ pos,
                             float* __restrict__ cosT, float* __restrict__ sinT) {
    int s = blockIdx.x;
    int d = threadIdx.x;
    float p = (float)pos[s];
    float inv = powf(10000.0f, -(float)(2 * d) / 128.0f);
    float ang = p * inv;
    cosT[s * 64 + d] = cosf(ang);
    sinT[s * 64 + d] = sinf(ang);
}

// ---------------- RoPE apply in-place on bf16, row stride ld ----------------
__global__ void rope_bf_k(unsigned short* __restrict__ x,
                          const float* __restrict__ cosT, const float* __restrict__ sinT,
                          int nh, int ld, float mul) {
    int idx = blockIdx.x * 256 + threadIdx.x;
    int d = idx & 63;
    int rest = idx >> 6;
    int h = rest % nh;
    int row = rest / nh;
    int s = row & (SLEN - 1);
    float c  = cosT[s * 64 + d] * mul;
    float sn = sinT[s * 64 + d] * mul;
    unsigned short* base = x + (size_t)row * ld + h * HD;
    float x1 = bf2f(base[d]), x2 = bf2f(base[d + 64]);
    base[d]      = bf16bits(x1 * c - x2 * sn);
    base[d + 64] = bf16bits(x2 * c + x1 * sn);
}

// ---------------- V transpose: bf16 [M][ldv] -> bf16 Vt[b*KVH+kvh][d=128][s=2048] ----------------
__global__ __launch_bounds__(256) void vtrans_k(const unsigned short* __restrict__ V, int ldv,
                                                unsigned short* __restrict__ Vt) {
    __shared__ unsigned short L[64][144];
    const int t = threadIdx.x;
    const int s0 = blockIdx.x * 64;
    const int bk = blockIdx.y;              // b*KVH + kvh
    const int b = bk >> 3, kvh = bk & 7;
    #pragma unroll
    for (int j = 0; j < 4; ++j) {
        int idx = t + j * 256;
        int row = idx >> 4;
        int c8  = (idx & 15) * 8;
        *(short8*)&L[row][c8] =
            *(const short8*)(V + ((size_t)b * SLEN + s0 + row) * ldv + kvh * HD + c8);
    }
    __syncthreads();
    {
        int d  = t >> 1;
        int sh = (t & 1) * 32;
        unsigned short tmp[32];
        #pragma unroll
        for (int j = 0; j < 32; ++j) tmp[j] = L[sh + j][d];
        unsigned short* dst = Vt + ((size_t)bk * HD + d) * SLEN + s0 + sh;
        #pragma unroll
        for (int j = 0; j < 4; ++j)
            *(short8*)(dst + j * 8) = *(const short8*)(tmp + j * 8);
    }
}

// ---------------- 256x256 bf16 MFMA GEMM-NT, BK=64, 8 waves, 4-phase interleave ----------------
// Per K-tile: 4 phases {ds_read A-quad (+B at q0) | stage 1 half-tile of t+1 | barrier |
// 16 MFMA | counted vmcnt at q1/q3 | barrier}. Stage order B0,B1,A0,A1; derived waits:
// vmcnt(4)@q1 (curr A1 landed before quads 2-3), vmcnt(2)@q3 (next B0/B1/A0 landed; A1 flies).
// LDS halves [128][64] slot^=(row&7) XOR swizzle (conflict-free, verified r8/r9).
template<typename CT>
__global__ __launch_bounds__(512, 1) void gemm256(
    const unsigned short* __restrict__ A, int lda,
    const unsigned short* __restrict__ W, int ldw,
    CT* __restrict__ C, int ldc,
    int M, int N, int K)
{
    __shared__ unsigned short Asl[2][2][128 * 64];   // [buf][half][row*64 + col]
    __shared__ unsigned short Bsl[2][2][128 * 64];

    const int t = threadIdx.x;           // 0..511
    const int w = t >> 6, lane = t & 63;

    // bijective XCD swizzle (nwg % 8 == 0 for all our launches)
    const int gx = gridDim.x;
    const int nwg = gx * gridDim.y;
    const int orig = blockIdx.y * gx + blockIdx.x;
    const int swzid = (orig & 7) * (nwg >> 3) + (orig >> 3);
    const int m0 = (swzid / gx) * 256, n0 = (swzid % gx) * 256;

    const int wm = (w >> 2) * 128;       // 0 / 128
    const int wn = (w & 3) * 64;         // 0,64,128,192
    const int fr = lane & 15, hi = lane >> 4;

    f32x4 acc[8][4];
    #pragma unroll
    for (int i = 0; i < 8; ++i)
        #pragma unroll
        for (int j = 0; j < 4; ++j)
            acc[i][j] = (f32x4){0.f, 0.f, 0.f, 0.f};

    // staging geometry: thread covers (row = j*64 + sr, slot = sl), dest linear in lane
    const int sr = t >> 3;
    const int sl = t & 7;
    const int wv512 = w * 512;

    // ---- prologue: stage tile 0 halves in order B0,B1,A0,A1; drain all but A1
    {
        #pragma unroll
        for (int hh = 0; hh < 4; ++hh) {
            #pragma unroll
            for (int j = 0; j < 2; ++j) {
                const int row = j * 64 + sr;
                const int scol = (sl ^ (row & 7)) << 3;
                if (hh < 2)
                    GLDS16(W + (size_t)(n0 + hh * 128 + row) * ldw + scol,
                           &Bsl[0][hh][j * 4096 + wv512]);
                else
                    GLDS16(A + (size_t)(m0 + (hh - 2) * 128 + row) * lda + scol,
                           &Asl[0][hh - 2][j * 4096 + wv512]);
            }
        }
        asm volatile("s_waitcnt vmcnt(2)" ::: "memory");
        __builtin_amdgcn_s_barrier();
        __builtin_amdgcn_sched_barrier(0);
    }

    const int NT = K >> 6;
    int buf = 0;
    for (int kt = 0; kt < NT; ++kt) {
        const unsigned short* Ah = Asl[buf][w >> 2];
        const unsigned short* Bh = Bsl[buf][(w & 3) >> 1];
        const bool pf = (kt + 1 < NT);
        const int k0n = (kt + 1) << 6;
        short8 bfr[4][2];

        #pragma unroll
        for (int q = 0; q < 4; ++q) {
            // ---- ds-reads for this phase
            if (q == 0) {
                #pragma unroll
                for (int j = 0; j < 4; ++j) {
                    const int lr = (wn & 127) + j * 16 + fr;
                    const int sz = lr & 7;
                    bfr[j][0] = *(const short8*)&Bh[lr * 64 + (((0 + hi) ^ sz) << 3)];
                    bfr[j][1] = *(const short8*)&Bh[lr * 64 + (((4 + hi) ^ sz) << 3)];
                }
            }
            short8 af[2][2];
            #pragma unroll
            for (int ii = 0; ii < 2; ++ii) {
                const int lr = q * 32 + ii * 16 + fr;
                const int sz = lr & 7;
                af[ii][0] = *(const short8*)&Ah[lr * 64 + (((0 + hi) ^ sz) << 3)];
                af[ii][1] = *(const short8*)&Ah[lr * 64 + (((4 + hi) ^ sz) << 3)];
            }

            // ---- stage half-tile q of tile kt+1 (order: q0=B0, q1=B1, q2=A0, q3=A1)
            if (pf) {
                #pragma unroll
                for (int j = 0; j < 2; ++j) {
                    const int row = j * 64 + sr;
                    const int scol = k0n + ((sl ^ (row & 7)) << 3);
                    if (q < 2)
                        GLDS16(W + (size_t)(n0 + q * 128 + row) * ldw + scol,
                               &Bsl[buf ^ 1][q][j * 4096 + wv512]);
                    else
                        GLDS16(A + (size_t)(m0 + (q - 2) * 128 + row) * lda + scol,
                               &Asl[buf ^ 1][q - 2][j * 4096 + wv512]);
                }
            }

            __builtin_amdgcn_sched_barrier(0);
            __builtin_amdgcn_s_barrier();
            __builtin_amdgcn_sched_barrier(0);

            // ---- 16 MFMA (quadrant q) — compiler inserts fine-grained lgkmcnt
            __builtin_amdgcn_s_setprio(1);
            #pragma unroll
            for (int ii = 0; ii < 2; ++ii)
                #pragma unroll
                for (int j = 0; j < 4; ++j) {
                    acc[q * 2 + ii][j] = __builtin_amdgcn_mfma_f32_16x16x32_bf16(
                        af[ii][0], bfr[j][0], acc[q * 2 + ii][j], 0, 0, 0);
                    acc[q * 2 + ii][j] = __builtin_amdgcn_mfma_f32_16x16x32_bf16(
                        af[ii][1], bfr[j][1], acc[q * 2 + ii][j], 0, 0, 0);
                }
            __builtin_amdgcn_s_setprio(0);

            // ---- counted waits (never 0 mid-stream)
            if (q == 1) {
                if (pf) asm volatile("s_waitcnt vmcnt(4)" ::: "memory");
                else    asm volatile("s_waitcnt vmcnt(0)" ::: "memory");
            } else if (q == 3 && pf) {
                asm volatile("s_waitcnt vmcnt(2)" ::: "memory");
            }
            __builtin_amdgcn_sched_barrier(0);
            __builtin_amdgcn_s_barrier();
            __builtin_amdgcn_sched_barrier(0);
        }
        buf ^= 1;
    }

    // epilogue: C/D layout col=lane&15, row=(lane>>4)*4+reg (verified)
    const int crow = (lane >> 4) * 4, ccol = lane & 15;
    #pragma unroll
    for (int i = 0; i < 8; ++i)
        #pragma unroll
        for (int j = 0; j < 4; ++j) {
            CT* cp = C + (size_t)(m0 + wm + i * 16 + crow) * ldc + (n0 + wn + j * 16 + ccol);
            #pragma unroll
            for (int r = 0; r < 4; ++r) {
                if constexpr (sizeof(CT) == 2)
                    cp[(size_t)r * ldc] = bf16bits(acc[i][j][r]);
                else
                    cp[(size_t)r * ldc] = acc[i][j][r];
            }
        }
}

// ---------------- MFMA flash attention: swapped 32x32x16, in-register softmax,
// LDS-shared double-buffered K/V with counted vmcnt (verified r8) ----------------
__global__ __launch_bounds__(256, 2) void flash_mfma32(
    const unsigned short* __restrict__ Qb, int ldq,   // rope'd, pre-scaled
    const unsigned short* __restrict__ Kb, int ldk,   // rope'd
    const unsigned short* __restrict__ Vt,            // [B*KVH][HD][SLEN]
    unsigned short* __restrict__ Ob)                  // [MROWS][DMODEL]
{
    __shared__ unsigned short Ks[2][64 * 128];   // [kv 64][d 128], rows 256B, swz (row&15)<<4
    __shared__ unsigned short Vs[2][128 * 64];   // [d 128][kv 64], rows 128B, swz (row&7)<<4

    const int t = threadIdx.x;
    const int wid = t >> 6, lane = t & 63;
    const int qt = (int)gridDim.x - 1 - (int)blockIdx.x;   // heavy blocks first
    const int bh = blockIdx.y;
    const int b = bh >> 5, h = bh & 31, kvh = h >> 2;
    const int lq = lane & 31;
    const int hl = lane >> 5;
    const int qw0 = qt * 128 + wid * 32;
    const int qg = qw0 + lq;
    const size_t qrowg = (size_t)b * SLEN + qg;

    const unsigned short* Kg0 = Kb + (size_t)b * SLEN * ldk + kvh * HD;
    const unsigned short* Vg0 = Vt + (size_t)(b * KVHEADS + kvh) * HD * SLEN;

    auto STAGE = [&](int buf, int kt) {   // 8 GLDS16 per thread
        const unsigned short* Kg = Kg0 + (size_t)kt * 64 * ldk;
        #pragma unroll
        for (int i = 0; i < 4; ++i) {
            int row = i * 16 + (t >> 4);
            int colel = ((((t & 15) << 4) ^ ((row & 15) << 4)) >> 1);
            GLDS16(Kg + (size_t)row * ldk + colel, &Ks[buf][i * 2048 + wid * 512]);
        }
        const unsigned short* Vg = Vg0 + kt * 64;
        #pragma unroll
        for (int i = 0; i < 4; ++i) {
            int row = i * 32 + (t >> 3);
            int colel = ((((t & 7) << 4) ^ ((row & 7) << 4)) >> 1);
            GLDS16(Vg + (size_t)row * SLEN + colel, &Vs[buf][i * 2048 + wid * 512]);
        }
    };

    STAGE(0, 0);
    short8 qf[8];
    {
        const unsigned short* qp = Qb + qrowg * ldq + h * HD + hl * 8;
        #pragma unroll
        for (int dt = 0; dt < 8; ++dt)
            qf[dt] = *(const short8*)(qp + dt * 16);
    }

    f32x16 accO[4];
    #pragma unroll
    for (int db = 0; db < 4; ++db)
        #pragma unroll
        for (int r = 0; r < 16; ++r) accO[db][r] = 0.f;
    float m_i = -INFINITY, l_i = 0.f;

    const int ntmax = 2 * qt + 2;   // uniform across waves
    int p = 0;
    for (int kt = 0; kt < ntmax; ++kt) {
        if (kt + 1 < ntmax) {
            STAGE(p ^ 1, kt + 1);
            asm volatile("s_waitcnt vmcnt(8)" ::: "memory");
        } else {
            asm volatile("s_waitcnt vmcnt(0)" ::: "memory");
        }
        __builtin_amdgcn_s_barrier();
        __builtin_amdgcn_sched_barrier(0);

        const unsigned short* Kp = Ks[p];
        const unsigned short* Vp = Vs[p];

        // ---- QK^T: S^T[kv 64][q 32], 16 MFMA
        f32x16 sc[2];
        #pragma unroll
        for (int blk = 0; blk < 2; ++blk) {
            #pragma unroll
            for (int r = 0; r < 16; ++r) sc[blk][r] = 0.f;
            __builtin_amdgcn_s_setprio(1);
            #pragma unroll
            for (int dt = 0; dt < 8; ++dt) {
                int krow = blk * 32 + lq;
                int kb = krow * 256 + ((dt * 32 + hl * 16) ^ ((krow & 15) << 4));
                short8 kf = *(const short8*)(Kp + (kb >> 1));
                sc[blk] = __builtin_amdgcn_mfma_f32_32x32x16_bf16(kf, qf[dt], sc[blk], 0, 0, 0);
            }
            __builtin_amdgcn_s_setprio(0);
        }

        // ---- causal mask
        if (kt * 64 + 63 > qw0) {
            #pragma unroll
            for (int blk = 0; blk < 2; ++blk)
                #pragma unroll
                for (int r = 0; r < 16; ++r) {
                    int kv = kt * 64 + blk * 32 + (r & 3) + 8 * (r >> 2) + 4 * hl;
                    if (kv > qg) sc[blk][r] = -INFINITY;
                }
        }

        // ---- row max (in-lane + one cross-half swap)
        float pmax = sc[0][0];
        #pragma unroll
        for (int r = 1; r < 16; ++r) pmax = fmaxf(pmax, sc[0][r]);
        #pragma unroll
        for (int r = 0; r < 16; ++r) pmax = fmaxf(pmax, sc[1][r]);
        {
            i32x2 mr = __builtin_amdgcn_permlane32_swap(__float_as_int(pmax), __float_as_int(pmax), false, false);
            pmax = fmaxf(__int_as_float(mr.x), __int_as_float(mr.y));
        }

        // ---- defer-max rescale (THR=8 log2 -> P<=256)
        if (!__all(pmax <= m_i + 8.0f)) {
            float mn = fmaxf(m_i, pmax);
            float al = exp2f(m_i - mn);
            m_i = mn;
            l_i *= al;
            #pragma unroll
            for (int db = 0; db < 4; ++db)
                #pragma unroll
                for (int r = 0; r < 16; ++r) accO[db][r] *= al;
        }

        // ---- exp + row sum
        float rs = 0.f;
        #pragma unroll
        for (int blk = 0; blk < 2; ++blk)
            #pragma unroll
            for (int r = 0; r < 16; ++r) {
                float pv = exp2f(sc[blk][r] - m_i);
                sc[blk][r] = pv;
                rs += pv;
            }
        {
            i32x2 sr = __builtin_amdgcn_permlane32_swap(__float_as_int(rs), __float_as_int(rs), false, false);
            rs = __int_as_float(sr.x) + __int_as_float(sr.y);
        }
        l_i += rs;

        // ---- pack P -> PV B-fragments in registers (verified r7)
        short8 pf[4];
        #pragma unroll
        for (int blk = 0; blk < 2; ++blk) {
            unsigned c01 = cvtpk(sc[blk][0],  sc[blk][1]);
            unsigned c23 = cvtpk(sc[blk][2],  sc[blk][3]);
            unsigned c45 = cvtpk(sc[blk][4],  sc[blk][5]);
            unsigned c67 = cvtpk(sc[blk][6],  sc[blk][7]);
            i32x2 sA = __builtin_amdgcn_permlane32_swap((int)c01, (int)c45, false, false);
            i32x2 sB = __builtin_amdgcn_permlane32_swap((int)c23, (int)c67, false, false);
            u32x4 f0 = {(unsigned)sA.x, (unsigned)sB.x, (unsigned)sA.y, (unsigned)sB.y};
            pf[blk * 2] = *(short8*)&f0;
            unsigned c89 = cvtpk(sc[blk][8],  sc[blk][9]);
            unsigned cab = cvtpk(sc[blk][10], sc[blk][11]);
            unsigned ccd = cvtpk(sc[blk][12], sc[blk][13]);
            unsigned cef = cvtpk(sc[blk][14], sc[blk][15]);
            i32x2 sC = __builtin_amdgcn_permlane32_swap((int)c89, (int)ccd, false, false);
            i32x2 sD = __builtin_amdgcn_permlane32_swap((int)cab, (int)cef, false, false);
            u32x4 f1 = {(unsigned)sC.x, (unsigned)sD.x, (unsigned)sC.y, (unsigned)sD.y};
            pf[blk * 2 + 1] = *(short8*)&f1;
        }

        // ---- PV: O^T[d][q] accum, 16 MFMA
        #pragma unroll
        for (int db = 0; db < 4; ++db) {
            __builtin_amdgcn_s_setprio(1);
            #pragma unroll
            for (int ks = 0; ks < 4; ++ks) {
                int vrow = db * 32 + lq;
                int vb = vrow * 128 + ((ks * 32 + hl * 16) ^ ((vrow & 7) << 4));
                short8 vf = *(const short8*)(Vp + (vb >> 1));
                accO[db] = __builtin_amdgcn_mfma_f32_32x32x16_bf16(vf, pf[ks], accO[db], 0, 0, 0);
            }
            __builtin_amdgcn_s_setprio(0);
        }

        __builtin_amdgcn_sched_barrier(0);
        __builtin_amdgcn_s_barrier();
        p ^= 1;
    }

    // ---- epilogue
    float inv = 1.0f / l_i;
    unsigned short* orow = Ob + qrowg * DMODEL + h * HD;
    #pragma unroll
    for (int db = 0; db < 4; ++db)
        #pragma unroll
        for (int rq = 0; rq < 4; ++rq) {
            unsigned w0 = cvtpk(accO[db][rq * 4 + 0] * inv, accO[db][rq * 4 + 1] * inv);
            unsigned w1 = cvtpk(accO[db][rq * 4 + 2] * inv, accO[db][rq * 4 + 3] * inv);
            uint2 pkd; pkd.x = w0; pkd.y = w1;
            *(uint2*)(orow + db * 32 + rq * 8 + hl * 4) = pkd;
        }
}

extern "C" void kernel_launch(void* const* d_in, const int* in_sizes, int n_in,
                              void* d_out, int out_size, void* d_ws, size_t ws_size,
                              hipStream_t stream) {
    const float* hs  = (const float*)d_in[0];
    const int*   pos = (const int*)d_in[1];
    const float* wq  = (const float*)d_in[2];
    const float* wk  = (const float*)d_in[3];
    const float* wv  = (const float*)d_in[4];
    const float* wo  = (const float*)d_in[5];
    float* out = (float*)d_out;

    char* ws = (char*)d_ws;
    unsigned short* hs_bf   = (unsigned short*)(ws);                        // 32 MB
    unsigned short* wqkv_bf = (unsigned short*)(ws + ((size_t)32  << 20));  // 48 MB [6144][4096]
    unsigned short* wo_bf   = (unsigned short*)(ws + ((size_t)80  << 20));  // 32 MB
    unsigned short* qkv_bf  = (unsigned short*)(ws + ((size_t)112 << 20));  // 48 MB [4096][6144]
    unsigned short* Vtb     = (unsigned short*)(ws + ((size_t)160 << 20));  // 8 MB
    unsigned short* Obf     = (unsigned short*)(ws + ((size_t)168 << 20));  // 32 MB
    float*          cosT    = (float*)(ws + ((size_t)200 << 20));           // 512 KB
    float*          sinT    = (float*)(ws + ((size_t)200 << 20) + (size_t)SLEN * 64 * 4);
    // total ~201 MB

    const long nHS = (long)MROWS * DMODEL;
    const long nWQ = (long)DMODEL * DMODEL;
    const long nWK = (long)KVDIM * DMODEL;

    rope_table_k<<<SLEN, 64, 0, stream>>>(pos, cosT, sinT);

    cast_k<<<nHS / 4 / 256, 256, 0, stream>>>(hs, hs_bf, nHS);
    cast_k<<<nWQ / 4 / 256, 256, 0, stream>>>(wq, wqkv_bf, nWQ);
    cast_k<<<nWK / 4 / 256, 256, 0, stream>>>(wk, wqkv_bf + (size_t)DMODEL * DMODEL, nWK);
    cast_k<<<nWK / 4 / 256, 256, 0, stream>>>(wv, wqkv_bf + (size_t)(DMODEL + KVDIM) * DMODEL, nWK);
    cast_k<<<nWQ / 4 / 256, 256, 0, stream>>>(wo, wo_bf, nWQ);

    // fused QKV projection: [4096][6144] bf16
    gemm256<unsigned short><<<dim3(NQKV/256, MROWS/256), 512, 0, stream>>>(
        hs_bf, DMODEL, wqkv_bf, DMODEL, qkv_bf, NQKV, MROWS, NQKV, DMODEL);

    // Q gets (1/sqrt(128)) * log2(e) folded in; K unscaled
    const float qmul = 0.088388347648318447f * 1.4426950408889634f;
    rope_bf_k<<<(MROWS * NHEADS  * 64) / 256, 256, 0, stream>>>(qkv_bf,          cosT, sinT, NHEADS,  NQKV, qmul);
    rope_bf_k<<<(MROWS * KVHEADS * 64) / 256, 256, 0, stream>>>(qkv_bf + DMODEL, cosT, sinT, KVHEADS, NQKV, 1.0f);
    vtrans_k<<<dim3(SLEN/64, BATCH*KVHEADS), 256, 0, stream>>>(qkv_bf + DMODEL + KVDIM, NQKV, Vtb);

    flash_mfma32<<<dim3(SLEN/128, BATCH*NHEADS), 256, 0, stream>>>(
        qkv_bf, NQKV, qkv_bf + DMODEL, NQKV, Vtb, Obf);

    gemm256<float><<<dim3(DMODEL/256, MROWS/256), 512, 0, stream>>>(
        Obf, DMODEL, wo_bf, DMODEL, out, DMODEL, MROWS, DMODEL, DMODEL);
}